// Round 2
// baseline (936.018 us; speedup 1.0000x reference)
//
#include <hip/hip_runtime.h>
#include <hip/hip_bf16.h>
#include <stdint.h>

// Problem constants
#define G 32
#define NN 1024
#define EE 16384
#define FIN 128
#define HID 1024
#define OUT 4096
#define BB 32
#define SS 256

typedef __bf16 bf16_t;
typedef __attribute__((ext_vector_type(8))) __bf16 bf16x8;
typedef __attribute__((ext_vector_type(4))) float f32x4;

// ---------------- workspace layout (bytes) ----------------
#define WS_FLAG     0            // 4 B (dtype flag: 1 = fp32 inputs, 0 = bf16)
// zeroed block (one memset of WS_ZERO_BYTES at WS_CNT):
#define WS_CNT      4096         // G*NN*4      = 131072
#define WS_WNODE    135168       // G*NN*4
#define WS_HSUM     266240       // G*NN*4
#define WS_WSUM     397312       // G*NN*4
#define WS_EMB      528384       // G*OUT*4     = 524288
#define WS_ZERO_BYTES 1048576    // covers cnt..emb exactly
#define WS_ROWPTR   1052672      // G*NN*4
#define WS_CURSOR   1183744      // G*NN*4
#define WS_POS2G    1314816      // BB*SS*4     = 32768
#define WS_B1F      1347584      // HID*4       = 4096
#define WS_B2F      1351680      // OUT*4       = 16384
#define WS_ESRC     1368064      // G*EE*4      = 2097152
#define WS_XBF      3465216      // G*NN*FIN*2  = 8388608
#define WS_AGG      11853824     // G*NN*FIN*2  = 8388608
#define WS_WCATT    20242432     // HID*256*2   = 524288
// total ~ 20.8 MB

__device__ inline float ldf(const void* p, size_t i, int f32) {
    return f32 ? ((const float*)p)[i] : (float)((const bf16_t*)p)[i];
}

// ---------------- dtype probe ----------------
// If the underlying data is fp32, even-indexed bf16 slots are fp32 low-mantissa
// bits -> random exponents; >=0xC0 occurs w.p. ~25%/sample. Genuine bf16
// normals never exceed exponent ~0x81.
__global__ __launch_bounds__(256) void probe_dtype_k(const void* x, int* flag) {
    __shared__ int s;
    int t = threadIdx.x;
    if (t == 0) s = 0;
    __syncthreads();
    const unsigned short* u = (const unsigned short*)x;
    int bad = 0;
    for (int i = t; i < 4096; i += 256) {
        unsigned short h = u[2 * i];
        int e = (h >> 7) & 0xFF;
        if (e >= 0xC0) bad = 1;
    }
    if (bad) atomicAdd(&s, 1);
    __syncthreads();
    if (t == 0) *flag = (s > 0) ? 1 : 0;
}

// canonicalize x -> bf16 xbf
__global__ __launch_bounds__(256) void conv_x_k(const void* x, const int* flag,
                                                bf16_t* __restrict__ xbf) {
    int f32 = *flag;
    size_t i = ((size_t)blockIdx.x * 256 + threadIdx.x) * 4;
    if (f32) {
        const float* xf = (const float*)x;
        bf16_t o0 = (bf16_t)xf[i], o1 = (bf16_t)xf[i + 1],
               o2 = (bf16_t)xf[i + 2], o3 = (bf16_t)xf[i + 3];
        unsigned short p[4] = {*(unsigned short*)&o0, *(unsigned short*)&o1,
                               *(unsigned short*)&o2, *(unsigned short*)&o3};
        *(uint2*)(xbf + i) = *(uint2*)p;
    } else {
        *(uint2*)(xbf + i) = *(const uint2*)((const bf16_t*)x + i);
    }
}

// canonicalize b1,b2 -> fp32
__global__ __launch_bounds__(256) void conv_b_k(const void* b1, const void* b2,
                                                const int* flag,
                                                float* __restrict__ b1f,
                                                float* __restrict__ b2f) {
    int f32 = *flag;
    int t = blockIdx.x * 256 + threadIdx.x;  // grid 20 blocks -> 5120 threads
    if (t < HID) b1f[t] = ldf(b1, t, f32);
    else if (t < HID + OUT) b2f[t - HID] = ldf(b2, t - HID, f32);
}

// ---------------- CSR build ----------------
__global__ __launch_bounds__(256) void count_edges_k(const int* __restrict__ ei,
                                                     int* __restrict__ cnt) {
    int idx = blockIdx.x * 256 + threadIdx.x;
    int g = idx >> 14, e = idx & (EE - 1);
    int dst = ei[(g * 2 + 1) * EE + e];
    atomicAdd(&cnt[g * NN + dst], 1);
}

__global__ __launch_bounds__(256) void wnode_k(const int* __restrict__ ei,
                                               const int* __restrict__ cnt,
                                               float* __restrict__ wnode) {
    int idx = blockIdx.x * 256 + threadIdx.x;
    int g = idx >> 14, e = idx & (EE - 1);
    int src = ei[g * 2 * EE + e];
    int dst = ei[(g * 2 + 1) * EE + e];
    int c = cnt[g * NN + dst];
    float w = 1.0f / (float)(c > 1 ? c : 1);
    atomicAdd(&wnode[g * NN + src], w);
}

__global__ __launch_bounds__(256) void scan_rowptr_k(const int* __restrict__ cnt,
                                                     int* __restrict__ rowptr,
                                                     int* __restrict__ cursor) {
    int g = blockIdx.x;
    const int* c = cnt + g * NN;
    __shared__ int part[256];
    int t = threadIdx.x;
    int c0 = c[t * 4], c1 = c[t * 4 + 1], c2 = c[t * 4 + 2], c3 = c[t * 4 + 3];
    int s = c0 + c1 + c2 + c3;
    part[t] = s;
    __syncthreads();
    for (int off = 1; off < 256; off <<= 1) {
        int v = (t >= off) ? part[t - off] : 0;
        __syncthreads();
        part[t] += v;
        __syncthreads();
    }
    int base = part[t] - s;
    int gi = g * NN + t * 4;
    int o0 = base, o1 = o0 + c0, o2 = o1 + c1, o3 = o2 + c2;
    rowptr[gi] = o0; rowptr[gi + 1] = o1; rowptr[gi + 2] = o2; rowptr[gi + 3] = o3;
    cursor[gi] = o0; cursor[gi + 1] = o1; cursor[gi + 2] = o2; cursor[gi + 3] = o3;
}

__global__ __launch_bounds__(256) void scatter_edges_k(const int* __restrict__ ei,
                                                       int* __restrict__ cursor,
                                                       int* __restrict__ esrc) {
    int idx = blockIdx.x * 256 + threadIdx.x;
    int g = idx >> 14, e = idx & (EE - 1);
    int src = ei[g * 2 * EE + e];
    int dst = ei[(g * 2 + 1) * EE + e];
    int p = atomicAdd(&cursor[g * NN + dst], 1);
    esrc[g * EE + p] = src;
}

// mean-aggregate xbf over incoming edges -> agg (bf16)
__global__ __launch_bounds__(256) void aggregate_k(const bf16_t* __restrict__ x,
                                                   const int* __restrict__ rowptr,
                                                   const int* __restrict__ cnt,
                                                   const int* __restrict__ esrc,
                                                   bf16_t* __restrict__ agg) {
    int g = blockIdx.x >> 9;
    int pair = blockIdx.x & 511;
    int n = pair * 2 + (threadIdx.x >> 7);
    int f = threadIdx.x & 127;
    int start = rowptr[g * NN + n];
    int deg = cnt[g * NN + n];
    const bf16_t* xg = x + (size_t)g * NN * FIN;
    const int* es = esrc + g * EE;
    float sum = 0.f;
    for (int i = 0; i < deg; ++i) {
        int s = es[start + i];
        sum += (float)xg[s * FIN + f];
    }
    float inv = 1.0f / (float)(deg > 1 ? deg : 1);
    agg[((size_t)g * NN + n) * FIN + f] = (bf16_t)(sum * inv);
}

// WcatT[n][k]: k<128 -> Wl1[k][n], else Wr1[k-128][n]   ([HID][256] bf16)
__global__ __launch_bounds__(256) void build_wcatT_k(const void* Wl1, const void* Wr1,
                                                     const int* flag,
                                                     bf16_t* __restrict__ wcatT) {
    int f32 = *flag;
    int n = blockIdx.x;
    int k = threadIdx.x;
    float v = (k < 128) ? ldf(Wl1, (size_t)k * HID + n, f32)
                        : ldf(Wr1, (size_t)(k - 128) * HID + n, f32);
    wcatT[n * 256 + k] = (bf16_t)v;
}

// Layer-1 GEMM: relu([agg|x] @ [Wl1;Wr1] + b1) with fused plain/weighted row-sums.
#define BKP 40
__global__ __launch_bounds__(256) void l1_gemm_k(const bf16_t* __restrict__ agg,
                                                 const bf16_t* __restrict__ x,
                                                 const bf16_t* __restrict__ wcatT,
                                                 const float* __restrict__ b1f,
                                                 const float* __restrict__ wnode,
                                                 float* __restrict__ hsum,
                                                 float* __restrict__ wsum) {
    int nt = blockIdx.x, mt = blockIdx.y, g = blockIdx.z;
    __shared__ bf16_t As[128 * BKP];
    __shared__ bf16_t Bs[128 * BKP];
    int tid = threadIdx.x;
    int lane = tid & 63, wave = tid >> 6;
    int quad = lane >> 4, l16 = lane & 15;
    int m0 = (wave >> 1) * 64, n0 = (wave & 1) * 64;

    f32x4 acc[4][4] = {};
    const size_t arow = ((size_t)g * NN + (size_t)mt * 128) * FIN;

    for (int kc = 0; kc < 8; ++kc) {
        int k0 = kc * 32;
        const bf16_t* asrc = (k0 < 128) ? (agg + arow + k0) : (x + arow + (k0 - 128));
        const bf16_t* bsrc = wcatT + (size_t)(nt * 128) * 256 + k0;
        #pragma unroll
        for (int i = 0; i < 2; ++i) {
            int gi = tid + i * 256;
            int row = gi >> 2, col = (gi & 3) * 8;
            *(bf16x8*)(&As[row * BKP + col]) = *(const bf16x8*)(asrc + row * FIN + col);
            *(bf16x8*)(&Bs[row * BKP + col]) = *(const bf16x8*)(bsrc + row * 256 + col);
        }
        __syncthreads();
        bf16x8 a[4], b[4];
        int kl = quad * 8;
        #pragma unroll
        for (int t4 = 0; t4 < 4; ++t4) {
            a[t4] = *(const bf16x8*)(&As[(m0 + t4 * 16 + l16) * BKP + kl]);
            b[t4] = *(const bf16x8*)(&Bs[(n0 + t4 * 16 + l16) * BKP + kl]);
        }
        #pragma unroll
        for (int ti = 0; ti < 4; ++ti)
            #pragma unroll
            for (int tj = 0; tj < 4; ++tj)
                acc[ti][tj] = __builtin_amdgcn_mfma_f32_16x16x32_bf16(a[ti], b[tj], acc[ti][tj], 0, 0, 0);
        __syncthreads();
    }

    const float* wn = wnode + (size_t)g * NN + mt * 128;
    #pragma unroll
    for (int tj = 0; tj < 4; ++tj) {
        int ng = nt * 128 + n0 + tj * 16 + l16;
        float bias = b1f[ng];
        float hs = 0.f, wsv = 0.f;
        #pragma unroll
        for (int ti = 0; ti < 4; ++ti) {
            int mb = m0 + ti * 16 + quad * 4;
            #pragma unroll
            for (int r = 0; r < 4; ++r) {
                float h = acc[ti][tj][r] + bias;
                h = h > 0.f ? h : 0.f;
                hs += h;
                wsv += wn[mb + r] * h;
            }
        }
        hs += __shfl_xor(hs, 16);  hs += __shfl_xor(hs, 32);
        wsv += __shfl_xor(wsv, 16); wsv += __shfl_xor(wsv, 32);
        if (quad == 0) {
            atomicAdd(&hsum[(size_t)g * HID + ng], hs);
            atomicAdd(&wsum[(size_t)g * HID + ng], wsv);
        }
    }
}

// Layer-2 collapsed GEMV (dtype-dual weight reads)
__global__ __launch_bounds__(256) void l2_gemv_k(const float* __restrict__ wsum,
                                                 const float* __restrict__ hsum,
                                                 const void* Wl2v, const void* Wr2v,
                                                 const int* flag,
                                                 float* __restrict__ emb_acc) {
    int f32 = *flag;
    int jc = blockIdx.x;   // 16
    int kc = blockIdx.y;   // 8
    int t = threadIdx.x;
    int j = jc * 256 + t;
    __shared__ float u1[G][128];
    __shared__ float u2[G][128];
    for (int i = 0; i < 16; ++i) {
        int idx = t + i * 256;
        int g = idx >> 7, kk = idx & 127;
        u1[g][kk] = wsum[g * HID + kc * 128 + kk] * (1.0f / 1024.0f);
        u2[g][kk] = hsum[g * HID + kc * 128 + kk] * (1.0f / 1024.0f);
    }
    __syncthreads();
    float acc[G] = {};
    if (f32) {
        const float* L = (const float*)Wl2v;
        const float* R = (const float*)Wr2v;
        for (int kk = 0; kk < 128; ++kk) {
            size_t krow = (size_t)(kc * 128 + kk);
            float wl = L[krow * OUT + j];
            float wr = R[krow * OUT + j];
            #pragma unroll
            for (int g = 0; g < G; ++g)
                acc[g] = fmaf(u1[g][kk], wl, fmaf(u2[g][kk], wr, acc[g]));
        }
    } else {
        const bf16_t* L = (const bf16_t*)Wl2v;
        const bf16_t* R = (const bf16_t*)Wr2v;
        for (int kk = 0; kk < 128; ++kk) {
            size_t krow = (size_t)(kc * 128 + kk);
            float wl = (float)L[krow * OUT + j];
            float wr = (float)R[krow * OUT + j];
            #pragma unroll
            for (int g = 0; g < G; ++g)
                acc[g] = fmaf(u1[g][kk], wl, fmaf(u2[g][kk], wr, acc[g]));
        }
    }
    #pragma unroll
    for (int g = 0; g < G; ++g)
        atomicAdd(&emb_acc[g * OUT + j], acc[g]);
}

// pos -> graph index (or -1); robust to bool stored as bytes or int32
__global__ __launch_bounds__(256) void pos2graph_k(const unsigned char* __restrict__ is_node,
                                                   int* __restrict__ p2g) {
    // byte-encoding: buf[256] = is_node[row1,s0] = 1; int32-encoding: byte 256
    // is byte0 of element 64 (False) = 0.
    int int_mode = (is_node[256] == 0);
    const int* in32 = (const int*)is_node;
    __shared__ int part[256];
    int t = threadIdx.x;
    unsigned char m[32];
    int c = 0;
    for (int i = 0; i < 32; ++i) {
        int idx = t * 32 + i;
        unsigned char v = int_mode ? (unsigned char)(in32[idx] != 0) : (unsigned char)(is_node[idx] != 0);
        m[i] = v;
        c += v ? 1 : 0;
    }
    part[t] = c;
    __syncthreads();
    for (int off = 1; off < 256; off <<= 1) {
        int v = (t >= off) ? part[t - off] : 0;
        __syncthreads();
        part[t] += v;
        __syncthreads();
    }
    int run = part[t] - c;
    for (int i = 0; i < 32; ++i) {
        int idx = t * 32 + i;
        p2g[idx] = m[i] ? (run < (G - 1) ? run : (G - 1)) : -1;
        if (m[i]) run++;
    }
}

// Final assembly, dtype-dual output
__global__ __launch_bounds__(256) void assemble_k(const int* __restrict__ p2g,
                                                  const int* __restrict__ input_ids,
                                                  const void* embedv,
                                                  const float* __restrict__ emb_acc,
                                                  const float* __restrict__ b2f,
                                                  const int* flag,
                                                  void* outv) {
    int f32 = *flag;
    int row = blockIdx.x;
    int t = threadIdx.x;
    int gidx = p2g[row];
    if (f32) {
        float* orow = (float*)outv + (size_t)row * OUT;
        if (gidx >= 0) {
            const float* src = emb_acc + (size_t)gidx * OUT;
            #pragma unroll
            for (int i = 0; i < 4; ++i) {
                int base = (t + i * 256) * 4;
                f32x4 v;
                #pragma unroll
                for (int k = 0; k < 4; ++k) v[k] = src[base + k] + b2f[base + k];
                *(f32x4*)(orow + base) = v;
            }
        } else {
            const uint4* s4 = (const uint4*)((const float*)embedv + (size_t)input_ids[row] * OUT);
            uint4* d4 = (uint4*)orow;
            #pragma unroll
            for (int i = 0; i < 4; ++i) d4[t + i * 256] = s4[t + i * 256];
        }
    } else {
        bf16_t* orow = (bf16_t*)outv + (size_t)row * OUT;
        if (gidx >= 0) {
            const float* src = emb_acc + (size_t)gidx * OUT;
            #pragma unroll
            for (int i = 0; i < 2; ++i) {
                int base = (t + i * 256) * 8;
                bf16x8 v;
                #pragma unroll
                for (int jj = 0; jj < 8; ++jj)
                    v[jj] = (bf16_t)(src[base + jj] + b2f[base + jj]);
                *(bf16x8*)(orow + base) = v;
            }
        } else {
            const uint4* s4 = (const uint4*)((const bf16_t*)embedv + (size_t)input_ids[row] * OUT);
            uint4* d4 = (uint4*)orow;
            d4[t] = s4[t];
            d4[t + 256] = s4[t + 256];
        }
    }
}

// ---------------- launch ----------------
extern "C" void kernel_launch(void* const* d_in, const int* in_sizes, int n_in,
                              void* d_out, int out_size, void* d_ws, size_t ws_size,
                              hipStream_t stream) {
    const void* x     = d_in[0];
    const int*  ei    = (const int*)d_in[1];
    const int*  ids   = (const int*)d_in[2];
    const unsigned char* isn = (const unsigned char*)d_in[3];
    const void* Wl1   = d_in[4];
    const void* Wr1   = d_in[5];
    const void* b1    = d_in[6];
    const void* Wl2   = d_in[7];
    const void* Wr2   = d_in[8];
    const void* b2    = d_in[9];
    const void* embed = d_in[10];

    char* ws = (char*)d_ws;
    int*    flag   = (int*)  (ws + WS_FLAG);
    int*    cnt    = (int*)  (ws + WS_CNT);
    float*  wnode  = (float*)(ws + WS_WNODE);
    float*  hsum   = (float*)(ws + WS_HSUM);
    float*  wsum   = (float*)(ws + WS_WSUM);
    float*  emb    = (float*)(ws + WS_EMB);
    int*    rowptr = (int*)  (ws + WS_ROWPTR);
    int*    cursor = (int*)  (ws + WS_CURSOR);
    int*    p2g    = (int*)  (ws + WS_POS2G);
    float*  b1f    = (float*)(ws + WS_B1F);
    float*  b2f    = (float*)(ws + WS_B2F);
    int*    esrc   = (int*)  (ws + WS_ESRC);
    bf16_t* xbf    = (bf16_t*)(ws + WS_XBF);
    bf16_t* agg    = (bf16_t*)(ws + WS_AGG);
    bf16_t* wcatT  = (bf16_t*)(ws + WS_WCATT);

    hipMemsetAsync(ws + WS_CNT, 0, WS_ZERO_BYTES, stream);

    probe_dtype_k<<<1, 256, 0, stream>>>(x, flag);
    conv_x_k<<<(G * NN * FIN) / 1024, 256, 0, stream>>>(x, flag, xbf);
    conv_b_k<<<20, 256, 0, stream>>>(b1, b2, flag, b1f, b2f);
    build_wcatT_k<<<HID, 256, 0, stream>>>(Wl1, Wr1, flag, wcatT);

    count_edges_k<<<G * EE / 256, 256, 0, stream>>>(ei, cnt);
    wnode_k<<<G * EE / 256, 256, 0, stream>>>(ei, cnt, wnode);
    scan_rowptr_k<<<G, 256, 0, stream>>>(cnt, rowptr, cursor);
    scatter_edges_k<<<G * EE / 256, 256, 0, stream>>>(ei, cursor, esrc);
    aggregate_k<<<G * 512, 256, 0, stream>>>(xbf, rowptr, cnt, esrc, agg);

    l1_gemm_k<<<dim3(8, 8, G), 256, 0, stream>>>(agg, xbf, wcatT, b1f, wnode, hsum, wsum);
    l2_gemv_k<<<dim3(16, 8), 256, 0, stream>>>(wsum, hsum, Wl2, Wr2, flag, emb);

    pos2graph_k<<<1, 256, 0, stream>>>(isn, p2g);
    assemble_k<<<BB * SS, 256, 0, stream>>>(p2g, ids, embed, emb, b2f, flag, d_out);
}